// Round 1
// baseline (1375.179 us; speedup 1.0000x reference)
//
#include <hip/hip_runtime.h>

#define TT 4
#define BB 16
#define CC 384
#define C2v 768
#define HWs 1024

// ---------- LIF step helpers (mirror reference op order, no fma contraction) ----------
__device__ __forceinline__ float lif_soft(float x, float& v) {
  // v = v + (x - v)/2 ; s = (v - 1 >= 0); v = v - s*1
  v = __fadd_rn(v, __fmul_rn(__fsub_rn(x, v), 0.5f));
  float s = (__fsub_rn(v, 1.0f) >= 0.0f) ? 1.0f : 0.0f;
  v = __fsub_rn(v, s);
  return s;
}
__device__ __forceinline__ float lif_hard(float x, float& v, float vth) {
  // v = v + (x - (v-0))/2 ; s = (v - vth >= 0); v = (1-s)*v
  v = __fadd_rn(v, __fmul_rn(__fsub_rn(x, v), 0.5f));
  float s = (__fsub_rn(v, vth) >= 0.0f) ? 1.0f : 0.0f;
  if (s != 0.0f) v = 0.0f;
  return s;
}

// ---------- precompute folded BN scale/bias (double precision) ----------
__global__ __launch_bounds__(768) void k_prep(const float* __restrict__ bn1,
                                              const float* __restrict__ bn2,
                                              const float* __restrict__ qkv,
                                              const float* __restrict__ rbn1,
                                              const float* __restrict__ rbn2,
                                              const float* __restrict__ proj,
                                              float* __restrict__ par) {
  int c = threadIdx.x;
  float* s1 = par;          float* o1 = par + 384;
  float* sA = par + 768;    float* oA = par + 1536;
  float* s2 = par + 2304;   float* o2 = par + 2688;
  float* sB = par + 3072;   float* oB = par + 3456;
  if (c < 384) {
    double a = (double)bn1[c] / sqrt((double)bn1[3*384+c] + 1e-5);
    s1[c] = (float)a;
    o1[c] = (float)((double)bn1[384+c] - (double)bn1[2*384+c]*a);
    double a2 = (double)rbn1[c] / sqrt((double)rbn1[3*384+c] + 1e-5);
    s2[c] = (float)a2;
    o2[c] = (float)((double)rbn1[384+c] - (double)rbn1[2*384+c]*a2);
    double a3 = (double)rbn2[c] / sqrt((double)rbn2[3*384+c] + 1e-5);
    double b3 = (double)rbn2[384+c] - (double)rbn2[2*384+c]*a3;
    double a4 = (double)proj[c] / sqrt((double)proj[3*384+c] + 1e-5);
    double b4 = (double)proj[384+c] - (double)proj[2*384+c]*a4;
    sB[c] = (float)(a3*a4);
    oB[c] = (float)(b3*a4 + b4);
  }
  if (c < 768) {
    double a5 = (double)bn2[c] / sqrt((double)bn2[3*768+c] + 1e-5);
    double b5 = (double)bn2[768+c] - (double)bn2[2*768+c]*a5;
    double a6 = (double)qkv[c] / sqrt((double)qkv[3*768+c] + 1e-5);
    double b6 = (double)qkv[768+c] - (double)qkv[2*768+c]*a6;
    sA[c] = (float)(a5*a6);
    oA[c] = (float)(b5*a6 + b6);
  }
}

// ---------- input LIF (hard reset, vth=1) ----------
__global__ __launch_bounds__(256) void k_lif_in(const float4* __restrict__ x, float4* __restrict__ xs) {
  const int stride = gridDim.x * blockDim.x;
  const int M4 = BB*CC*HWs/4; // 1572864
  for (int i = blockIdx.x*blockDim.x + threadIdx.x; i < M4; i += stride) {
    float4 v = {0.f,0.f,0.f,0.f};
    #pragma unroll
    for (int t = 0; t < TT; ++t) {
      float4 xi = x[(size_t)t*M4 + i];
      float4 s;
      s.x = lif_hard(xi.x, v.x, 1.0f); s.y = lif_hard(xi.y, v.y, 1.0f);
      s.z = lif_hard(xi.z, v.z, 1.0f); s.w = lif_hard(xi.w, v.w, 1.0f);
      xs[(size_t)t*M4 + i] = s;
    }
  }
}

// ---------- 1x1 conv as GEMM: Y[n,o,p] = sum_c W[o,c]*X[n,c,p], epilogue scale/bias ----------
__global__ __launch_bounds__(256) void k_gemm(const float* __restrict__ X, const float* __restrict__ W,
                                              const float* __restrict__ scale, const float* __restrict__ bias,
                                              float* __restrict__ Y, int M) {
  __shared__ float Ws2[32][68];
  __shared__ float Xs[32][64];
  const int n  = blockIdx.z;
  const int o0 = blockIdx.y * 64;
  const int p0 = blockIdx.x * 64;
  const float* Xn = X + (size_t)n * CC * HWs;
  const int tid = threadIdx.x;
  const int tx = tid & 15, ty = tid >> 4;
  float acc[4][4] = {};
  for (int k0 = 0; k0 < CC; k0 += 32) {
    #pragma unroll
    for (int q = 0; q < 2; ++q) {
      int idx = tid + q*256;
      int orow = idx >> 3, kc = (idx & 7) * 4;
      float4 wv = *(const float4*)&W[(size_t)(o0+orow)*CC + k0 + kc];
      Ws2[kc+0][orow] = wv.x; Ws2[kc+1][orow] = wv.y;
      Ws2[kc+2][orow] = wv.z; Ws2[kc+3][orow] = wv.w;
      int krow = idx >> 4, pc = (idx & 15)*4;
      *(float4*)&Xs[krow][pc] = *(const float4*)&Xn[(size_t)(k0+krow)*HWs + p0 + pc];
    }
    __syncthreads();
    #pragma unroll
    for (int k = 0; k < 32; ++k) {
      float4 a4 = *(const float4*)&Ws2[k][ty*4];
      float4 b4 = *(const float4*)&Xs[k][tx*4];
      float a[4] = {a4.x, a4.y, a4.z, a4.w};
      float b[4] = {b4.x, b4.y, b4.z, b4.w};
      #pragma unroll
      for (int i = 0; i < 4; ++i)
        #pragma unroll
        for (int j = 0; j < 4; ++j)
          acc[i][j] = fmaf(a[i], b[j], acc[i][j]);
    }
    __syncthreads();
  }
  #pragma unroll
  for (int i = 0; i < 4; ++i) {
    int o = o0 + ty*4 + i;
    float sc = scale[o], bi = bias[o];
    float4 r;
    r.x = fmaf(acc[i][0], sc, bi);
    r.y = fmaf(acc[i][1], sc, bi);
    r.z = fmaf(acc[i][2], sc, bi);
    r.w = fmaf(acc[i][3], sc, bi);
    *(float4*)&Y[((size_t)n*M + o)*HWs + p0 + tx*4] = r;
  }
}

// ---------- depthwise 3x3 over virtually-padded (pad value pv[c]) 32x32 -> 32x32 ----------
__global__ __launch_bounds__(256) void k_dw(const float* __restrict__ X, const float* __restrict__ Wd,
                                            const float* __restrict__ pvArr, float* __restrict__ Y) {
  __shared__ float tile[34*34];
  const int bid = blockIdx.x;
  const int n = bid / CC, c = bid % CC;
  const float pv = pvArr[c];
  const float* Xp = X + ((size_t)n*CC + c) * HWs;
  const int tid = threadIdx.x;
  for (int idx = tid; idx < 1156; idx += 256) {
    int ph = idx / 34, pw = idx % 34;
    int oh = ph - 1, ow = pw - 1;
    float val = pv;
    if ((unsigned)oh < 32u && (unsigned)ow < 32u) val = Xp[oh*32 + ow];
    tile[idx] = val;
  }
  float wk[9];
  #pragma unroll
  for (int k = 0; k < 9; ++k) wk[k] = Wd[c*9 + k];
  __syncthreads();
  float* Yp = Y + ((size_t)n*CC + c) * HWs;
  #pragma unroll
  for (int r = 0; r < 4; ++r) {
    int oidx = tid + r*256;
    int h = oidx >> 5, w = oidx & 31;
    float acc = 0.0f;
    #pragma unroll
    for (int i = 0; i < 3; ++i)
      #pragma unroll
      for (int j = 0; j < 3; ++j)
        acc = fmaf(wk[i*3+j], tile[(h+i)*34 + (w+j)], acc);
    Yp[oidx] = acc;
  }
}

// ---------- qk path: LIF(soft) -> spatial sum -> LIF(hard, 0.5) -> gate[t,b,c] ----------
__global__ __launch_bounds__(256) void k_qk(const float* __restrict__ y6, float* __restrict__ gate) {
  __shared__ float red[256];
  __shared__ float sums[TT];
  const int bid = blockIdx.x;
  const int b = bid / CC, c = bid % CC;
  const int tid = threadIdx.x;
  float4 v = {0.f,0.f,0.f,0.f};
  for (int t = 0; t < TT; ++t) {
    int n = t*BB + b;
    const float4 xi = *(const float4*)&y6[((size_t)n*C2v + c)*HWs + tid*4];
    float4 s;
    s.x = lif_soft(xi.x, v.x); s.y = lif_soft(xi.y, v.y);
    s.z = lif_soft(xi.z, v.z); s.w = lif_soft(xi.w, v.w);
    float partial = s.x + s.y + s.z + s.w;
    __syncthreads();
    red[tid] = partial;
    __syncthreads();
    for (int off = 128; off > 0; off >>= 1) {
      if (tid < off) red[tid] += red[tid+off];
      __syncthreads();
    }
    if (tid == 0) sums[t] = red[0];
  }
  if (tid == 0) {
    float u = 0.0f;
    for (int t = 0; t < TT; ++t) {
      float g = lif_hard(sums[t], u, 0.5f);
      gate[(size_t)(t*BB + b)*CC + c] = g;
    }
  }
}

// ---------- v path: LIF(soft) * gate -> att ----------
__global__ __launch_bounds__(256) void k_vatt(const float* __restrict__ y6, const float* __restrict__ gate,
                                              float* __restrict__ att) {
  const int bid = blockIdx.x;
  const int b = bid / CC, c = bid % CC;
  const int tid = threadIdx.x;
  float4 v = {0.f,0.f,0.f,0.f};
  for (int t = 0; t < TT; ++t) {
    int n = t*BB + b;
    const float4 xi = *(const float4*)&y6[((size_t)n*C2v + (CC + c))*HWs + tid*4];
    float4 s;
    s.x = lif_soft(xi.x, v.x); s.y = lif_soft(xi.y, v.y);
    s.z = lif_soft(xi.z, v.z); s.w = lif_soft(xi.w, v.w);
    float g = gate[(size_t)n*CC + c];
    float4 r = {s.x*g, s.y*g, s.z*g, s.w*g};
    *(float4*)&att[((size_t)n*CC + c)*HWs + tid*4] = r;
  }
}

// ---------- output LIF (soft) * scale ----------
__global__ __launch_bounds__(256) void k_lif_out(const float4* __restrict__ z, const float* __restrict__ scale,
                                                 float4* __restrict__ out) {
  const int stride = gridDim.x * blockDim.x;
  const int M4 = BB*CC*HWs/4;
  const float sc = scale[0];
  for (int i = blockIdx.x*blockDim.x + threadIdx.x; i < M4; i += stride) {
    float4 v = {0.f,0.f,0.f,0.f};
    #pragma unroll
    for (int t = 0; t < TT; ++t) {
      float4 xi = z[(size_t)t*M4 + i];
      float4 s;
      s.x = lif_soft(xi.x, v.x)*sc; s.y = lif_soft(xi.y, v.y)*sc;
      s.z = lif_soft(xi.z, v.z)*sc; s.w = lif_soft(xi.w, v.w)*sc;
      out[(size_t)t*M4 + i] = s;
    }
  }
}

extern "C" void kernel_launch(void* const* d_in, const int* in_sizes, int n_in,
                              void* d_out, int out_size, void* d_ws, size_t ws_size,
                              hipStream_t stream) {
  const float* x      = (const float*)d_in[0];
  const float* r1_w1  = (const float*)d_in[1];
  const float* r1_bn1 = (const float*)d_in[2];
  const float* r1_dw  = (const float*)d_in[3];
  const float* r1_pw  = (const float*)d_in[4];
  const float* r1_bn2 = (const float*)d_in[5];
  const float* qkv_bn = (const float*)d_in[6];
  const float* r2_w1  = (const float*)d_in[7];
  const float* r2_bn1 = (const float*)d_in[8];
  const float* r2_dw  = (const float*)d_in[9];
  const float* r2_pw  = (const float*)d_in[10];
  const float* r2_bn2 = (const float*)d_in[11];
  const float* proj_bn= (const float*)d_in[12];
  const float* scale  = (const float*)d_in[13];

  float* ws = (float*)d_ws;
  const size_t SEG = 25165824; // T*B*C*H*W floats
  float* bufA = ws;              // xs -> (y6 low) -> y2'
  float* bufB = ws + SEG;        // y2 -> (y6 high) -> y3'
  float* bufC = ws + 2*SEG;      // y3 -> att -> z
  float* y6   = ws;              // spans bufA+bufB (2*SEG floats)
  float* gate = ws + 3*SEG;      // T*B*C = 24576
  float* par  = ws + 3*SEG + 24576;
  float* s1 = par,        *o1 = par + 384;
  float* sA = par + 768,  *oA = par + 1536;
  float* s2 = par + 2304, *o2 = par + 2688;
  float* sB = par + 3072, *oB = par + 3456;

  k_prep<<<1, 768, 0, stream>>>(r1_bn1, r1_bn2, qkv_bn, r2_bn1, r2_bn2, proj_bn, par);
  k_lif_in<<<2048, 256, 0, stream>>>((const float4*)x, (float4*)bufA);
  // repconv1
  k_gemm<<<dim3(16, 6, 64), 256, 0, stream>>>(bufA, r1_w1, s1, o1, bufB, 384);
  k_dw<<<24576, 256, 0, stream>>>(bufB, r1_dw, o1, bufC);
  k_gemm<<<dim3(16, 12, 64), 256, 0, stream>>>(bufC, r1_pw, sA, oA, y6, 768);
  // spike attention gating
  k_qk<<<6144, 256, 0, stream>>>(y6, gate);
  k_vatt<<<6144, 256, 0, stream>>>(y6, gate, bufC);
  // repconv2
  k_gemm<<<dim3(16, 6, 64), 256, 0, stream>>>(bufC, r2_w1, s2, o2, bufA, 384);
  k_dw<<<24576, 256, 0, stream>>>(bufA, r2_dw, o2, bufB);
  k_gemm<<<dim3(16, 6, 64), 256, 0, stream>>>(bufB, r2_pw, sB, oB, bufC, 384);
  // output LIF * scale
  k_lif_out<<<2048, 256, 0, stream>>>((const float4*)bufC, scale, (float4*)d_out);
}

// Round 3
// 821.155 us; speedup vs baseline: 1.6747x; 1.6747x over previous
//
#include <hip/hip_runtime.h>

typedef _Float16 f16;
typedef __attribute__((ext_vector_type(8))) _Float16 f16x8;
typedef __attribute__((ext_vector_type(4))) float f32x4;

#define TT 4
#define BB 16
#define CC 384

// ---------- LIF step helpers (mirror reference op order, no fma contraction) ----------
__device__ __forceinline__ float lif_soft(float x, float& v) {
  v = __fadd_rn(v, __fmul_rn(__fsub_rn(x, v), 0.5f));
  float s = (__fsub_rn(v, 1.0f) >= 0.0f) ? 1.0f : 0.0f;
  v = __fsub_rn(v, s);
  return s;
}
__device__ __forceinline__ float lif_hard(float x, float& v, float vth) {
  v = __fadd_rn(v, __fmul_rn(__fsub_rn(x, v), 0.5f));
  float s = (__fsub_rn(v, vth) >= 0.0f) ? 1.0f : 0.0f;
  if (s != 0.0f) v = 0.0f;
  return s;
}

// ---------- BN param folding (double precision) ----------
__global__ __launch_bounds__(768) void k_prep(const float* __restrict__ bn1,
                                              const float* __restrict__ bn2,
                                              const float* __restrict__ qkv,
                                              const float* __restrict__ rbn1,
                                              const float* __restrict__ rbn2,
                                              const float* __restrict__ proj,
                                              float* __restrict__ par) {
  int c = threadIdx.x;
  float* s1 = par;          float* o1 = par + 384;
  float* sA = par + 768;    float* oA = par + 1536;
  float* s2 = par + 2304;   float* o2 = par + 2688;
  float* sB = par + 3072;   float* oB = par + 3456;
  if (c < 384) {
    double a = (double)bn1[c] / sqrt((double)bn1[3*384+c] + 1e-5);
    s1[c] = (float)a;
    o1[c] = (float)((double)bn1[384+c] - (double)bn1[2*384+c]*a);
    double a2 = (double)rbn1[c] / sqrt((double)rbn1[3*384+c] + 1e-5);
    s2[c] = (float)a2;
    o2[c] = (float)((double)rbn1[384+c] - (double)rbn1[2*384+c]*a2);
    double a3 = (double)rbn2[c] / sqrt((double)rbn2[3*384+c] + 1e-5);
    double b3 = (double)rbn2[384+c] - (double)rbn2[2*384+c]*a3;
    double a4 = (double)proj[c] / sqrt((double)proj[3*384+c] + 1e-5);
    double b4 = (double)proj[384+c] - (double)proj[2*384+c]*a4;
    sB[c] = (float)(a3*a4);
    oB[c] = (float)(b3*a4 + b4);
  }
  if (c < 768) {
    double a5 = (double)bn2[c] / sqrt((double)bn2[3*768+c] + 1e-5);
    double b5 = (double)bn2[768+c] - (double)bn2[2*768+c]*a5;
    double a6 = (double)qkv[c] / sqrt((double)qkv[3*768+c] + 1e-5);
    double b6 = (double)qkv[768+c] - (double)qkv[2*768+c]*a6;
    sA[c] = (float)(a5*a6);
    oA[c] = (float)(b5*a6 + b6);
  }
}

// ---------- weight split: w = a + 2^-11 * b  (both f16, b scaled to stay normal) ----------
__global__ __launch_bounds__(256) void k_wsplit(const float* __restrict__ w,
                                                f16* __restrict__ wa, f16* __restrict__ wb, int n) {
  int i = blockIdx.x * 256 + threadIdx.x;
  if (i < n) {
    float x = w[i];
    f16 a = (f16)x;
    wa[i] = a;
    wb[i] = (f16)((x - (float)a) * 2048.0f);
  }
}

// ---------- input LIF: NCHW fp32 -> NHWC f16 spikes (LDS transpose) ----------
__global__ __launch_bounds__(256) void k_lif_in(const float* __restrict__ x, f16* __restrict__ xs) {
  __shared__ float tile[64][65];   // [c][p]
  const int p0 = blockIdx.x * 64, c0 = blockIdx.y * 64, b = blockIdx.z;
  const int l = threadIdx.x & 63, q = threadIdx.x >> 6;
  float v[16];
  #pragma unroll
  for (int j = 0; j < 16; ++j) v[j] = 0.0f;
  for (int t = 0; t < TT; ++t) {
    __syncthreads();
    #pragma unroll
    for (int j = 0; j < 16; ++j) {
      int ci = q + j*4;
      tile[ci][l] = x[(((size_t)(t*BB + b)*CC + c0 + ci) << 10) + p0 + l];
    }
    __syncthreads();
    #pragma unroll
    for (int j = 0; j < 16; ++j) {
      int pi = q + j*4;   // thread owns element (c = l, p = pi) across t
      float s = lif_hard(tile[l][pi], v[j], 1.0f);
      xs[((size_t)(t*BB + b)*1024 + p0 + pi)*CC + c0 + l] = (f16)s;
    }
  }
}

// ---------- global_load_lds staging with XOR-swizzled source (m173/m201 pattern) ----------
__device__ __forceinline__ void stage16(const f16* g, int row0, int k0,
                                        f16* l, int inst, int lane) {
  int loff = inst*1024 + lane*16;            // linear LDS byte offset of this lane's 16B
  int row = loff >> 7;                       // 128B per row (64 f16)
  int col = loff & 127;
  int srccol = col ^ ((row & 7) << 4);       // inverse-swizzle the SOURCE
  const char* src = (const char*)g + (size_t)(row0 + row)*768 + k0*2 + srccol;
  char* dst = (char*)l + inst*1024;          // wave-uniform base; HW adds lane*16
  __builtin_amdgcn_global_load_lds((const __attribute__((address_space(1))) void*)src,
                                   (__attribute__((address_space(3))) void*)dst, 16, 0, 0);
}

// fragment read with matching swizzle
__device__ __forceinline__ f16x8 fragld(const f16* l, int row, int kb) {
  int off = row*128 + (kb ^ ((row & 7) << 4));
  return *(const f16x8*)((const char*)l + off);
}

// ---------- split-f16 MFMA GEMM: out[m][o] = bn( sum_c X[m][c]*W[o][c] ) ----------
// X = X1 + 2^-11 X2 (NP==3) or exact f16 X1 (NP==2); W = Wa + 2^-11 Wb always.
template<int NP>
__global__ __launch_bounds__(256, 2) void k_gemm(const f16* __restrict__ X1, const f16* __restrict__ X2,
    const f16* __restrict__ Wa, const f16* __restrict__ Wb,
    const float* __restrict__ scale, const float* __restrict__ bias,
    float* __restrict__ out0, float* __restrict__ out1) {
  __shared__ __align__(16) f16 lX1[128*64];
  __shared__ __align__(16) f16 lW1[128*64];
  __shared__ __align__(16) f16 lW2[128*64];
  __shared__ __align__(16) f16 lX2[(NP == 3) ? 128*64 : 64];
  const int m0 = blockIdx.y * 128;
  const int o0 = blockIdx.x * 128;
  const int lane = threadIdx.x & 63, wid = threadIdx.x >> 6;
  const int wr = wid >> 1, wc = wid & 1;
  const int fr = lane & 15, fq = lane >> 4;
  f32x4 acc_h[4][4], acc_l[4][4];
  #pragma unroll
  for (int i = 0; i < 4; ++i)
    #pragma unroll
    for (int j = 0; j < 4; ++j) { acc_h[i][j] = (f32x4){0,0,0,0}; acc_l[i][j] = (f32x4){0,0,0,0}; }

  for (int k0 = 0; k0 < 384; k0 += 64) {
    if (NP == 3) {
      if (wid == 0)      { for (int i = 0; i < 16; ++i) stage16(X1, m0, k0, lX1, i, lane); }
      else if (wid == 1) { for (int i = 0; i < 16; ++i) stage16(X2, m0, k0, lX2, i, lane); }
      else if (wid == 2) { for (int i = 0; i < 16; ++i) stage16(Wa, o0, k0, lW1, i, lane); }
      else               { for (int i = 0; i < 16; ++i) stage16(Wb, o0, k0, lW2, i, lane); }
    } else {
      if (wid < 2)       { for (int i = 0; i < 8;  ++i) stage16(X1, m0, k0, lX1, wid*8 + i, lane); }
      else if (wid == 2) { for (int i = 0; i < 16; ++i) stage16(Wa, o0, k0, lW1, i, lane); }
      else               { for (int i = 0; i < 16; ++i) stage16(Wb, o0, k0, lW2, i, lane); }
    }
    __syncthreads();
    #pragma unroll
    for (int ks = 0; ks < 2; ++ks) {
      const int kb = ks*64 + fq*16;
      f16x8 a1[4], b1[4], b2[4], a2[4];
      #pragma unroll
      for (int mi = 0; mi < 4; ++mi) a1[mi] = fragld(lX1, wr*64 + mi*16 + fr, kb);
      #pragma unroll
      for (int oi = 0; oi < 4; ++oi) {
        b1[oi] = fragld(lW1, wc*64 + oi*16 + fr, kb);
        b2[oi] = fragld(lW2, wc*64 + oi*16 + fr, kb);
      }
      if (NP == 3) {
        #pragma unroll
        for (int mi = 0; mi < 4; ++mi) a2[mi] = fragld(lX2, wr*64 + mi*16 + fr, kb);
      }
      #pragma unroll
      for (int mi = 0; mi < 4; ++mi)
        #pragma unroll
        for (int oi = 0; oi < 4; ++oi) {
          acc_h[mi][oi] = __builtin_amdgcn_mfma_f32_16x16x32_f16(a1[mi], b1[oi], acc_h[mi][oi], 0, 0, 0);
          acc_l[mi][oi] = __builtin_amdgcn_mfma_f32_16x16x32_f16(a1[mi], b2[oi], acc_l[mi][oi], 0, 0, 0);
          if (NP == 3)
            acc_l[mi][oi] = __builtin_amdgcn_mfma_f32_16x16x32_f16(a2[mi], b1[oi], acc_l[mi][oi], 0, 0, 0);
        }
    }
    __syncthreads();
  }
  #pragma unroll
  for (int oi = 0; oi < 4; ++oi) {
    int o = o0 + wc*64 + oi*16 + fr;
    float sc = scale[o], bi = bias[o];
    float* op = out0; int oc = o;
    if (o >= 384) { op = out1; oc = o - 384; }
    #pragma unroll
    for (int mi = 0; mi < 4; ++mi) {
      f32x4 h = acc_h[mi][oi], lo2 = acc_l[mi][oi];
      #pragma unroll
      for (int r = 0; r < 4; ++r) {
        int m = m0 + wr*64 + mi*16 + fq*4 + r;
        float y = fmaf(0.00048828125f, lo2[r], h[r]);   // + 2^-11 * low
        op[(size_t)m*384 + oc] = fmaf(y, sc, bi);
      }
    }
  }
}

// ---------- depthwise 3x3, NHWC, fp32 in -> split-f16 pair out, virtual pad pv[c] ----------
__global__ __launch_bounds__(256) void k_dw(const float* __restrict__ in, const float* __restrict__ wd,
                                            const float* __restrict__ pv,
                                            f16* __restrict__ outA, f16* __restrict__ outB) {
  const int ct = blockIdx.x, h = blockIdx.y, n = blockIdx.z;
  const int c = ct*64 + (threadIdx.x & 63);
  const int wq = threadIdx.x >> 6;
  float w9[9];
  #pragma unroll
  for (int i = 0; i < 9; ++i) w9[i] = wd[c*9 + i];
  const float pvc = pv[c];
  const float* base = in + (size_t)n*1024*CC;
  for (int wi = 0; wi < 8; ++wi) {
    int w = wq*8 + wi;
    float acc = 0.0f;
    #pragma unroll
    for (int dh = -1; dh <= 1; ++dh)
      #pragma unroll
      for (int dw = -1; dw <= 1; ++dw) {
        int hh = h + dh, ww = w + dw;
        float vv = ((unsigned)hh < 32u && (unsigned)ww < 32u) ? base[(size_t)(hh*32 + ww)*CC + c] : pvc;
        acc = fmaf(w9[(dh+1)*3 + dw + 1], vv, acc);
      }
    f16 a = (f16)acc;
    size_t off = ((size_t)n*1024 + h*32 + w)*CC + c;
    outA[off] = a;
    outB[off] = (f16)((acc - (float)a) * 2048.0f);
  }
}

// ---------- qk path stage 1: LIF(soft) + spatial partial sums ----------
__global__ __launch_bounds__(256) void k_qksum(const float* __restrict__ y6qk, float* __restrict__ partial) {
  __shared__ float red[4][4][64];
  const int ps = blockIdx.x, ct = blockIdx.y, b = blockIdx.z;
  const int l = threadIdx.x & 63, pg = threadIdx.x >> 6;
  const int c = ct*64 + l;
  float sums[4] = {0,0,0,0};
  for (int i = 0; i < 32; ++i) {
    int p = ps*128 + pg*32 + i;
    float v = 0.0f;
    #pragma unroll
    for (int t = 0; t < TT; ++t) {
      float xv = y6qk[((size_t)(t*BB + b)*1024 + p)*CC + c];
      sums[t] += lif_soft(xv, v);
    }
  }
  #pragma unroll
  for (int t = 0; t < TT; ++t) red[pg][t][l] = sums[t];
  __syncthreads();
  int t2 = threadIdx.x >> 6;
  float tot = red[0][t2][l] + red[1][t2][l] + red[2][t2][l] + red[3][t2][l];
  partial[(((size_t)ps*4 + t2)*BB + b)*CC + c] = tot;
}

// ---------- qk path stage 2: combine slices + LIF(hard 0.5) -> gate ----------
__global__ __launch_bounds__(256) void k_gate(const float* __restrict__ partial, float* __restrict__ gate) {
  int g = blockIdx.x*256 + threadIdx.x;   // 6144 = 16*384
  int b = g / CC, c = g % CC;
  float sums[4];
  #pragma unroll
  for (int t = 0; t < TT; ++t) {
    float s = 0.0f;
    for (int ps = 0; ps < 8; ++ps) s += partial[(((size_t)ps*4 + t)*BB + b)*CC + c];
    sums[t] = s;
  }
  float v = 0.0f;
  #pragma unroll
  for (int t = 0; t < TT; ++t)
    gate[(size_t)(t*BB + b)*CC + c] = lif_hard(sums[t], v, 0.5f);
}

// ---------- v path: LIF(soft) * gate -> att (exact f16 0/1) ----------
__global__ __launch_bounds__(256) void k_vatt(const float* __restrict__ y6v, const float* __restrict__ gate,
                                              f16* __restrict__ att) {
  const int psl = blockIdx.x, ct = blockIdx.y, b = blockIdx.z;
  const int l = threadIdx.x & 63, pg = threadIdx.x >> 6;
  const int c = ct*64 + l;
  float g4[4];
  #pragma unroll
  for (int t = 0; t < TT; ++t) g4[t] = gate[(size_t)(t*BB + b)*CC + c];
  for (int i = 0; i < 16; ++i) {
    int p = psl*64 + pg*16 + i;
    float v = 0.0f;
    #pragma unroll
    for (int t = 0; t < TT; ++t) {
      size_t off = ((size_t)(t*BB + b)*1024 + p)*CC + c;
      float s = lif_soft(y6v[off], v);
      att[off] = (f16)(s * g4[t]);
    }
  }
}

// ---------- output LIF: NHWC fp32 -> NCHW fp32, soft LIF * scale (LDS transpose) ----------
__global__ __launch_bounds__(256) void k_lif_out(const float* __restrict__ z, const float* __restrict__ scalep,
                                                 float* __restrict__ out) {
  __shared__ float tile[64][65];  // [p][c]
  const int p0 = blockIdx.x * 64, c0 = blockIdx.y * 64, b = blockIdx.z;
  const int l = threadIdx.x & 63, q = threadIdx.x >> 6;
  const float sc = scalep[0];
  float v[16];
  #pragma unroll
  for (int j = 0; j < 16; ++j) v[j] = 0.0f;
  for (int t = 0; t < TT; ++t) {
    __syncthreads();
    #pragma unroll
    for (int j = 0; j < 16; ++j) {
      int pi = q + j*4;
      tile[pi][l] = z[((size_t)(t*BB + b)*1024 + p0 + pi)*CC + c0 + l];
    }
    __syncthreads();
    #pragma unroll
    for (int j = 0; j < 16; ++j) {
      int ci = q + j*4;   // thread owns element (c = ci, p = l) across t
      float s = lif_soft(tile[l][ci], v[j]) * sc;
      out[(((size_t)(t*BB + b))*CC + c0 + ci)*1024 + p0 + l] = s;
    }
  }
}

extern "C" void kernel_launch(void* const* d_in, const int* in_sizes, int n_in,
                              void* d_out, int out_size, void* d_ws, size_t ws_size,
                              hipStream_t stream) {
  const float* x      = (const float*)d_in[0];
  const float* r1_w1  = (const float*)d_in[1];
  const float* r1_bn1 = (const float*)d_in[2];
  const float* r1_dw  = (const float*)d_in[3];
  const float* r1_pw  = (const float*)d_in[4];
  const float* r1_bn2 = (const float*)d_in[5];
  const float* qkv_bn = (const float*)d_in[6];
  const float* r2_w1  = (const float*)d_in[7];
  const float* r2_bn1 = (const float*)d_in[8];
  const float* r2_dw  = (const float*)d_in[9];
  const float* r2_pw  = (const float*)d_in[10];
  const float* r2_bn2 = (const float*)d_in[11];
  const float* proj_bn= (const float*)d_in[12];
  const float* scale  = (const float*)d_in[13];

  float* ws = (float*)d_ws;
  const size_t SEG = 12582912;              // 48 MB in floats
  // layout: W0 [0, SEG) f16 region; W1 [SEG, 3*SEG) fp32; W2 [3*SEG, 4*SEG) f16; W3 [4*SEG, 6*SEG) fp32
  float* W0f = ws;
  float* W1  = ws + SEG;
  float* W2f = ws + 3*SEG;
  float* W3  = ws + 4*SEG;
  f16* xs   = (f16*)W0f;                    // spikes -> p1a -> p2b
  f16* p1a  = (f16*)W0f;
  f16* p2b  = (f16*)W0f;
  f16* p1b  = (f16*)W2f;                    // -> att -> p2a
  f16* att  = (f16*)W2f;
  f16* p2a  = (f16*)W2f;
  float* t1   = W1;                         // gemm1 out -> y6qk -> t2
  float* y6qk = W1;
  float* t2   = W1;
  float* y6v  = W3;                         // -> z
  float* z    = W3;

  f16* wsp = (f16*)(ws + 6*SEG);            // 1.77 MB shared region (phases A/B/C)
  f16* w1a = wsp,            *w1b = wsp + 147456;
  f16* pwa = wsp + 294912,   *pwb = wsp + 589824;        // phase A (r1)
  float* partial = (float*)wsp;                          // phase B: 196608 floats
  float* gate    = (float*)wsp + 196608;                 //          +24576
  f16* q1a = wsp,            *q1b = wsp + 147456;        // phase C (r2)
  f16* qpa = wsp + 294912,   *qpb = wsp + 442368;

  float* par = ws + 6*SEG + 442368;         // 3840 floats of BN params
  float* s1 = par,        *o1 = par + 384;
  float* sA = par + 768,  *oA = par + 1536;
  float* s2 = par + 2304, *o2 = par + 2688;
  float* sB = par + 3072, *oB = par + 3456;

  k_prep<<<1, 768, 0, stream>>>(r1_bn1, r1_bn2, qkv_bn, r2_bn1, r2_bn2, proj_bn, par);
  k_wsplit<<<576, 256, 0, stream>>>(r1_w1, w1a, w1b, 147456);
  k_wsplit<<<1152, 256, 0, stream>>>(r1_pw, pwa, pwb, 294912);
  k_lif_in<<<dim3(16, 6, 16), 256, 0, stream>>>(x, xs);
  // repconv1
  k_gemm<2><<<dim3(3, 512), 256, 0, stream>>>(xs, (const f16*)nullptr, w1a, w1b, s1, o1, t1, t1);
  k_dw<<<dim3(6, 32, 64), 256, 0, stream>>>(t1, r1_dw, o1, p1a, p1b);
  k_gemm<3><<<dim3(6, 512), 256, 0, stream>>>(p1a, p1b, pwa, pwb, sA, oA, y6qk, y6v);
  // spike attention gating
  k_qksum<<<dim3(8, 6, 16), 256, 0, stream>>>(y6qk, partial);
  k_gate<<<24, 256, 0, stream>>>(partial, gate);
  k_vatt<<<dim3(16, 6, 16), 256, 0, stream>>>(y6v, gate, att);
  // repconv2 (re-split r2 weights into the shared region after gate consumed)
  k_wsplit<<<576, 256, 0, stream>>>(r2_w1, q1a, q1b, 147456);
  k_wsplit<<<576, 256, 0, stream>>>(r2_pw, qpa, qpb, 147456);
  k_gemm<2><<<dim3(3, 512), 256, 0, stream>>>(att, (const f16*)nullptr, q1a, q1b, s2, o2, t2, t2);
  k_dw<<<dim3(6, 32, 64), 256, 0, stream>>>(t2, r2_dw, o2, p2a, p2b);
  k_gemm<3><<<dim3(3, 512), 256, 0, stream>>>(p2a, p2b, qpa, qpb, sB, oB, z, z);
  // output LIF * scale (NHWC -> NCHW)
  k_lif_out<<<dim3(16, 6, 16), 256, 0, stream>>>(z, scale, (float*)d_out);
}

// Round 6
// 592.492 us; speedup vs baseline: 2.3210x; 1.3859x over previous
//
#include <hip/hip_runtime.h>

typedef _Float16 f16;
typedef __attribute__((ext_vector_type(8))) _Float16 f16x8;
typedef __attribute__((ext_vector_type(4))) float f32x4;

#define TT 4
#define BB 16
#define CC 384

// ---------- LIF step helpers (mirror reference op order, no fma contraction) ----------
__device__ __forceinline__ float lif_soft(float x, float& v) {
  v = __fadd_rn(v, __fmul_rn(__fsub_rn(x, v), 0.5f));
  float s = (__fsub_rn(v, 1.0f) >= 0.0f) ? 1.0f : 0.0f;
  v = __fsub_rn(v, s);
  return s;
}
__device__ __forceinline__ float lif_hard(float x, float& v, float vth) {
  v = __fadd_rn(v, __fmul_rn(__fsub_rn(x, v), 0.5f));
  float s = (__fsub_rn(v, vth) >= 0.0f) ? 1.0f : 0.0f;
  if (s != 0.0f) v = 0.0f;
  return s;
}

// ---------- BN param folding (double precision) ----------
__global__ __launch_bounds__(768) void k_prep(const float* __restrict__ bn1,
                                              const float* __restrict__ bn2,
                                              const float* __restrict__ qkv,
                                              const float* __restrict__ rbn1,
                                              const float* __restrict__ rbn2,
                                              const float* __restrict__ proj,
                                              float* __restrict__ par) {
  int c = threadIdx.x;
  float* s1 = par;          float* o1 = par + 384;
  float* sA = par + 768;    float* oA = par + 1536;
  float* s2 = par + 2304;   float* o2 = par + 2688;
  float* sB = par + 3072;   float* oB = par + 3456;
  if (c < 384) {
    double a = (double)bn1[c] / sqrt((double)bn1[3*384+c] + 1e-5);
    s1[c] = (float)a;
    o1[c] = (float)((double)bn1[384+c] - (double)bn1[2*384+c]*a);
    double a2 = (double)rbn1[c] / sqrt((double)rbn1[3*384+c] + 1e-5);
    s2[c] = (float)a2;
    o2[c] = (float)((double)rbn1[384+c] - (double)rbn1[2*384+c]*a2);
    double a3 = (double)rbn2[c] / sqrt((double)rbn2[3*384+c] + 1e-5);
    double b3 = (double)rbn2[384+c] - (double)rbn2[2*384+c]*a3;
    double a4 = (double)proj[c] / sqrt((double)proj[3*384+c] + 1e-5);
    double b4 = (double)proj[384+c] - (double)proj[2*384+c]*a4;
    sB[c] = (float)(a3*a4);
    oB[c] = (float)(b3*a4 + b4);
  }
  if (c < 768) {
    double a5 = (double)bn2[c] / sqrt((double)bn2[3*768+c] + 1e-5);
    double b5 = (double)bn2[768+c] - (double)bn2[2*768+c]*a5;
    double a6 = (double)qkv[c] / sqrt((double)qkv[3*768+c] + 1e-5);
    double b6 = (double)qkv[768+c] - (double)qkv[2*768+c]*a6;
    sA[c] = (float)(a5*a6);
    oA[c] = (float)(b5*a6 + b6);
  }
}

// ---------- weight split: w = a + 2^-11 * b ----------
__global__ __launch_bounds__(256) void k_wsplit(const float* __restrict__ w,
                                                f16* __restrict__ wa, f16* __restrict__ wb, int n) {
  int i = blockIdx.x * 256 + threadIdx.x;
  if (i < n) {
    float x = w[i];
    f16 a = (f16)x;
    wa[i] = a;
    wb[i] = (f16)((x - (float)a) * 2048.0f);
  }
}

// ---------- input LIF: NCHW fp32 -> NHWC f16 spikes (LDS transpose) ----------
__global__ __launch_bounds__(256) void k_lif_in(const float* __restrict__ x, f16* __restrict__ xs) {
  __shared__ float tile[64][65];   // [c][p]
  const int p0 = blockIdx.x * 64, c0 = blockIdx.y * 64, b = blockIdx.z;
  const int l = threadIdx.x & 63, q = threadIdx.x >> 6;
  float v[16];
  #pragma unroll
  for (int j = 0; j < 16; ++j) v[j] = 0.0f;
  for (int t = 0; t < TT; ++t) {
    __syncthreads();
    #pragma unroll
    for (int j = 0; j < 16; ++j) {
      int ci = q + j*4;
      tile[ci][l] = x[(((size_t)(t*BB + b)*CC + c0 + ci) << 10) + p0 + l];
    }
    __syncthreads();
    #pragma unroll
    for (int j = 0; j < 16; ++j) {
      int pi = q + j*4;
      float s = lif_hard(tile[l][pi], v[j], 1.0f);
      xs[((size_t)(t*BB + b)*1024 + p0 + pi)*CC + c0 + l] = (f16)s;
    }
  }
}

// ---------- staging: global -> LDS, 64B rows, swizzle col ^= ((row>>1)&3)<<4 ----------
// LDS[row][col] = G[row0+row][k0bytes + (col ^ sw(row))]; involution applied again on read.
__device__ __forceinline__ void stage_arr(const f16* __restrict__ g, int row0, int k0,
                                          f16* dst, int lane, int i0, int i1) {
  #pragma unroll
  for (int i = i0; i < i1; ++i) {
    int loff = i*1024 + lane*16;              // linear byte offset within 8 KB tile
    int row = loff >> 6, col = loff & 63;
    int scol = col ^ (((row >> 1) & 3) << 4); // inverse-swizzled SOURCE column
    const char* src = (const char*)g + (size_t)(row0 + row)*768 + (size_t)(k0*2) + scol;
    __builtin_amdgcn_global_load_lds((const __attribute__((address_space(1))) void*)src,
                                     (__attribute__((address_space(3))) void*)((char*)dst + i*1024),
                                     16, 0, 0);
  }
}

// fragment read with matching swizzle (row in [0,128), fq selects 16B k-slot)
__device__ __forceinline__ f16x8 fragld32(const f16* arr, int row, int fq) {
  int off = row*64 + ((fq*16) ^ (((row >> 1) & 3) << 4));
  return *(const f16x8*)((const char*)arr + off);
}

// ---------- split-f16 MFMA GEMM, 2-phase double-buffered pipeline (BK=32) ----------
// out[m][o] = bn( sum_c X[m][c]*W[o][c] );  X = X1 + 2^-11 X2 (NP==3) or exact X1 (NP==2).
template<int NP>
__global__ __launch_bounds__(256, 2) void k_gemm(const f16* __restrict__ X1, const f16* __restrict__ X2,
    const f16* __restrict__ Wa, const f16* __restrict__ Wb,
    const float* __restrict__ scale, const float* __restrict__ bias,
    float* __restrict__ out0, float* __restrict__ out1) {
  constexpr int ARR = (NP == 3) ? 4 : 3;            // tiles per buffer
  __shared__ __align__(16) f16 lds[2*ARR*4096];     // 8 KB per tile (128 rows x 64 B)
  const int m0 = blockIdx.y * 128;
  const int o0 = blockIdx.x * 128;
  const int lane = threadIdx.x & 63, wid = threadIdx.x >> 6;
  const int wr = wid >> 1, wc = wid & 1;
  const int fr = lane & 15, fq = lane >> 4;
  f32x4 acc_h[4][4], acc_l[4][4];
  #pragma unroll
  for (int i = 0; i < 4; ++i)
    #pragma unroll
    for (int j = 0; j < 4; ++j) { acc_h[i][j] = (f32x4){0,0,0,0}; acc_l[i][j] = (f32x4){0,0,0,0}; }

  auto stage_all = [&](int buf, int k0) {
    f16* base = lds + buf*(ARR*4096);
    if (NP == 3) {
      if (wid == 0)      stage_arr(X1, m0, k0, base,          lane, 0, 8);
      else if (wid == 1) stage_arr(X2, m0, k0, base + 4096,   lane, 0, 8);
      else if (wid == 2) stage_arr(Wa, o0, k0, base + 2*4096, lane, 0, 8);
      else               stage_arr(Wb, o0, k0, base + 3*4096, lane, 0, 8);
    } else {
      if (wid == 0)      stage_arr(X1, m0, k0, base,          lane, 0, 4);
      else if (wid == 1) stage_arr(X1, m0, k0, base,          lane, 4, 8);
      else if (wid == 2) stage_arr(Wa, o0, k0, base + 4096,   lane, 0, 8);
      else               stage_arr(Wb, o0, k0, base + 2*4096, lane, 0, 8);
    }
  };

  // prologue: stage K-tile 0 into buf 0 (syncthreads drains vmcnt+lgkmcnt)
  stage_all(0, 0);
  __syncthreads();

  for (int it = 0; it < 12; ++it) {                 // K = 384 = 12 x 32
    const int cur = it & 1;
    if (it < 11) stage_all(cur ^ 1, (it + 1)*32);   // issue next tile FIRST (hides HBM latency)
    const f16* bX1 = lds + cur*(ARR*4096);
    const f16* bW1 = (NP == 3) ? bX1 + 2*4096 : bX1 + 4096;
    const f16* bW2 = (NP == 3) ? bX1 + 3*4096 : bX1 + 2*4096;
    f16x8 a1[4], b1[4], b2[4];
    #pragma unroll
    for (int mi = 0; mi < 4; ++mi) a1[mi] = fragld32(bX1, wr*64 + mi*16 + fr, fq);
    #pragma unroll
    for (int oi = 0; oi < 4; ++oi) {
      b1[oi] = fragld32(bW1, wc*64 + oi*16 + fr, fq);
      b2[oi] = fragld32(bW2, wc*64 + oi*16 + fr, fq);
    }
    if (NP == 3) {
      const f16* bX2 = bX1 + 4096;
      f16x8 a2[4];
      #pragma unroll
      for (int mi = 0; mi < 4; ++mi) a2[mi] = fragld32(bX2, wr*64 + mi*16 + fr, fq);
      #pragma unroll
      for (int mi = 0; mi < 4; ++mi)
        #pragma unroll
        for (int oi = 0; oi < 4; ++oi) {
          acc_h[mi][oi] = __builtin_amdgcn_mfma_f32_16x16x32_f16(a1[mi], b1[oi], acc_h[mi][oi], 0, 0, 0);
          acc_l[mi][oi] = __builtin_amdgcn_mfma_f32_16x16x32_f16(a1[mi], b2[oi], acc_l[mi][oi], 0, 0, 0);
          acc_l[mi][oi] = __builtin_amdgcn_mfma_f32_16x16x32_f16(a2[mi], b1[oi], acc_l[mi][oi], 0, 0, 0);
        }
    } else {
      #pragma unroll
      for (int mi = 0; mi < 4; ++mi)
        #pragma unroll
        for (int oi = 0; oi < 4; ++oi) {
          acc_h[mi][oi] = __builtin_amdgcn_mfma_f32_16x16x32_f16(a1[mi], b1[oi], acc_h[mi][oi], 0, 0, 0);
          acc_l[mi][oi] = __builtin_amdgcn_mfma_f32_16x16x32_f16(a1[mi], b2[oi], acc_l[mi][oi], 0, 0, 0);
        }
    }
    __syncthreads();   // drains this wave's stage loads (vmcnt) + releases buf for overwrite
  }

  #pragma unroll
  for (int oi = 0; oi < 4; ++oi) {
    int o = o0 + wc*64 + oi*16 + fr;
    float sc = scale[o], bi = bias[o];
    float* op = out0; int oc = o;
    if (o >= 384) { op = out1; oc = o - 384; }
    #pragma unroll
    for (int mi = 0; mi < 4; ++mi) {
      f32x4 h = acc_h[mi][oi], lo2 = acc_l[mi][oi];
      #pragma unroll
      for (int r = 0; r < 4; ++r) {
        int m = m0 + wr*64 + mi*16 + fq*4 + r;
        float y = fmaf(0.00048828125f, lo2[r], h[r]);   // + 2^-11 * low
        op[(size_t)m*384 + oc] = fmaf(y, sc, bi);
      }
    }
  }
}

// ---------- depthwise 3x3, NHWC, fp32 in -> split-f16 pair out, virtual pad pv[c] ----------
__global__ __launch_bounds__(256) void k_dw(const float* __restrict__ in, const float* __restrict__ wd,
                                            const float* __restrict__ pv,
                                            f16* __restrict__ outA, f16* __restrict__ outB) {
  const int ct = blockIdx.x, h = blockIdx.y, n = blockIdx.z;
  const int c = ct*64 + (threadIdx.x & 63);
  const int wq = threadIdx.x >> 6;
  float w9[9];
  #pragma unroll
  for (int i = 0; i < 9; ++i) w9[i] = wd[c*9 + i];
  const float pvc = pv[c];
  const float* base = in + (size_t)n*1024*CC;
  for (int wi = 0; wi < 8; ++wi) {
    int w = wq*8 + wi;
    float acc = 0.0f;
    #pragma unroll
    for (int dh = -1; dh <= 1; ++dh)
      #pragma unroll
      for (int dw = -1; dw <= 1; ++dw) {
        int hh = h + dh, ww = w + dw;
        float vv = ((unsigned)hh < 32u && (unsigned)ww < 32u) ? base[(size_t)(hh*32 + ww)*CC + c] : pvc;
        acc = fmaf(w9[(dh+1)*3 + dw + 1], vv, acc);
      }
    f16 a = (f16)acc;
    size_t off = ((size_t)n*1024 + h*32 + w)*CC + c;
    outA[off] = a;
    outB[off] = (f16)((acc - (float)a) * 2048.0f);
  }
}

// ---------- qk path stage 1: LIF(soft) + spatial partial sums ----------
__global__ __launch_bounds__(256) void k_qksum(const float* __restrict__ y6qk, float* __restrict__ partial) {
  __shared__ float red[4][4][64];
  const int ps = blockIdx.x, ct = blockIdx.y, b = blockIdx.z;
  const int l = threadIdx.x & 63, pg = threadIdx.x >> 6;
  const int c = ct*64 + l;
  float sums[4] = {0,0,0,0};
  for (int i = 0; i < 32; ++i) {
    int p = ps*128 + pg*32 + i;
    float v = 0.0f;
    #pragma unroll
    for (int t = 0; t < TT; ++t) {
      float xv = y6qk[((size_t)(t*BB + b)*1024 + p)*CC + c];
      sums[t] += lif_soft(xv, v);
    }
  }
  #pragma unroll
  for (int t = 0; t < TT; ++t) red[pg][t][l] = sums[t];
  __syncthreads();
  int t2 = threadIdx.x >> 6;
  float tot = red[0][t2][l] + red[1][t2][l] + red[2][t2][l] + red[3][t2][l];
  partial[(((size_t)ps*4 + t2)*BB + b)*CC + c] = tot;
}

// ---------- qk path stage 2: combine slices + LIF(hard 0.5) -> gate ----------
__global__ __launch_bounds__(256) void k_gate(const float* __restrict__ partial, float* __restrict__ gate) {
  int g = blockIdx.x*256 + threadIdx.x;   // 6144 = 16*384
  int b = g / CC, c = g % CC;
  float sums[4];
  #pragma unroll
  for (int t = 0; t < TT; ++t) {
    float s = 0.0f;
    for (int ps = 0; ps < 8; ++ps) s += partial[(((size_t)ps*4 + t)*BB + b)*CC + c];
    sums[t] = s;
  }
  float v = 0.0f;
  #pragma unroll
  for (int t = 0; t < TT; ++t)
    gate[(size_t)(t*BB + b)*CC + c] = lif_hard(sums[t], v, 0.5f);
}

// ---------- v path: LIF(soft) * gate -> att (exact f16 0/1) ----------
__global__ __launch_bounds__(256) void k_vatt(const float* __restrict__ y6v, const float* __restrict__ gate,
                                              f16* __restrict__ att) {
  const int psl = blockIdx.x, ct = blockIdx.y, b = blockIdx.z;
  const int l = threadIdx.x & 63, pg = threadIdx.x >> 6;
  const int c = ct*64 + l;
  float g4[4];
  #pragma unroll
  for (int t = 0; t < TT; ++t) g4[t] = gate[(size_t)(t*BB + b)*CC + c];
  for (int i = 0; i < 16; ++i) {
    int p = psl*64 + pg*16 + i;
    float v = 0.0f;
    #pragma unroll
    for (int t = 0; t < TT; ++t) {
      size_t off = ((size_t)(t*BB + b)*1024 + p)*CC + c;
      float s = lif_soft(y6v[off], v);
      att[off] = (f16)(s * g4[t]);
    }
  }
}

// ---------- output LIF: NHWC fp32 -> NCHW fp32, soft LIF * scale (LDS transpose) ----------
__global__ __launch_bounds__(256) void k_lif_out(const float* __restrict__ z, const float* __restrict__ scalep,
                                                 float* __restrict__ out) {
  __shared__ float tile[64][65];  // [p][c]
  const int p0 = blockIdx.x * 64, c0 = blockIdx.y * 64, b = blockIdx.z;
  const int l = threadIdx.x & 63, q = threadIdx.x >> 6;
  const float sc = scalep[0];
  float v[16];
  #pragma unroll
  for (int j = 0; j < 16; ++j) v[j] = 0.0f;
  for (int t = 0; t < TT; ++t) {
    __syncthreads();
    #pragma unroll
    for (int j = 0; j < 16; ++j) {
      int pi = q + j*4;
      tile[pi][l] = z[((size_t)(t*BB + b)*1024 + p0 + pi)*CC + c0 + l];
    }
    __syncthreads();
    #pragma unroll
    for (int j = 0; j < 16; ++j) {
      int ci = q + j*4;
      float s = lif_soft(tile[l][ci], v[j]) * sc;
      out[(((size_t)(t*BB + b))*CC + c0 + ci)*1024 + p0 + l] = s;
    }
  }
}

extern "C" void kernel_launch(void* const* d_in, const int* in_sizes, int n_in,
                              void* d_out, int out_size, void* d_ws, size_t ws_size,
                              hipStream_t stream) {
  const float* x      = (const float*)d_in[0];
  const float* r1_w1  = (const float*)d_in[1];
  const float* r1_bn1 = (const float*)d_in[2];
  const float* r1_dw  = (const float*)d_in[3];
  const float* r1_pw  = (const float*)d_in[4];
  const float* r1_bn2 = (const float*)d_in[5];
  const float* qkv_bn = (const float*)d_in[6];
  const float* r2_w1  = (const float*)d_in[7];
  const float* r2_bn1 = (const float*)d_in[8];
  const float* r2_dw  = (const float*)d_in[9];
  const float* r2_pw  = (const float*)d_in[10];
  const float* r2_bn2 = (const float*)d_in[11];
  const float* proj_bn= (const float*)d_in[12];
  const float* scale  = (const float*)d_in[13];

  float* ws = (float*)d_ws;
  const size_t SEG = 12582912;              // 48 MB in floats
  float* W0f = ws;
  float* W1  = ws + SEG;
  float* W2f = ws + 3*SEG;
  float* W3  = ws + 4*SEG;
  f16* xs   = (f16*)W0f;                    // spikes -> p1a -> p2b
  f16* p1a  = (f16*)W0f;
  f16* p2b  = (f16*)W0f;
  f16* p1b  = (f16*)W2f;                    // -> att -> p2a
  f16* att  = (f16*)W2f;
  f16* p2a  = (f16*)W2f;
  float* t1   = W1;                         // gemm1 out -> y6qk -> t2
  float* y6qk = W1;
  float* t2   = W1;
  float* y6v  = W3;                         // -> z
  float* z    = W3;

  f16* wsp = (f16*)(ws + 6*SEG);            // shared region (phases A/B/C)
  f16* w1a = wsp,            *w1b = wsp + 147456;
  f16* pwa = wsp + 294912,   *pwb = wsp + 589824;        // phase A (r1)
  float* partial = (float*)wsp;                          // phase B: 196608 floats
  float* gate    = (float*)wsp + 196608;                 //          +24576
  f16* q1a = wsp,            *q1b = wsp + 147456;        // phase C (r2)
  f16* qpa = wsp + 294912,   *qpb = wsp + 442368;

  float* par = ws + 6*SEG + 442368;         // 3840 floats of BN params
  float* s1 = par,        *o1 = par + 384;
  float* sA = par + 768,  *oA = par + 1536;
  float* s2 = par + 2304, *o2 = par + 2688;
  float* sB = par + 3072, *oB = par + 3456;

  k_prep<<<1, 768, 0, stream>>>(r1_bn1, r1_bn2, qkv_bn, r2_bn1, r2_bn2, proj_bn, par);
  k_wsplit<<<576, 256, 0, stream>>>(r1_w1, w1a, w1b, 147456);
  k_wsplit<<<1152, 256, 0, stream>>>(r1_pw, pwa, pwb, 294912);
  k_lif_in<<<dim3(16, 6, 16), 256, 0, stream>>>(x, xs);
  // repconv1
  k_gemm<2><<<dim3(3, 512), 256, 0, stream>>>(xs, (const f16*)nullptr, w1a, w1b, s1, o1, t1, t1);
  k_dw<<<dim3(6, 32, 64), 256, 0, stream>>>(t1, r1_dw, o1, p1a, p1b);
  k_gemm<3><<<dim3(6, 512), 256, 0, stream>>>(p1a, p1b, pwa, pwb, sA, oA, y6qk, y6v);
  // spike attention gating
  k_qksum<<<dim3(8, 6, 16), 256, 0, stream>>>(y6qk, partial);
  k_gate<<<24, 256, 0, stream>>>(partial, gate);
  k_vatt<<<dim3(16, 6, 16), 256, 0, stream>>>(y6v, gate, att);
  // repconv2 (re-split r2 weights into the shared region after gate consumed)
  k_wsplit<<<576, 256, 0, stream>>>(r2_w1, q1a, q1b, 147456);
  k_wsplit<<<576, 256, 0, stream>>>(r2_pw, qpa, qpb, 147456);
  k_gemm<2><<<dim3(3, 512), 256, 0, stream>>>(att, (const f16*)nullptr, q1a, q1b, s2, o2, t2, t2);
  k_dw<<<dim3(6, 32, 64), 256, 0, stream>>>(t2, r2_dw, o2, p2a, p2b);
  k_gemm<3><<<dim3(3, 512), 256, 0, stream>>>(p2a, p2b, qpa, qpb, sB, oB, z, z);
  // output LIF * scale (NHWC -> NCHW)
  k_lif_out<<<dim3(16, 6, 16), 256, 0, stream>>>(z, scale, (float*)d_out);
}

// Round 7
// 572.214 us; speedup vs baseline: 2.4033x; 1.0354x over previous
//
#include <hip/hip_runtime.h>

typedef _Float16 f16;
typedef __attribute__((ext_vector_type(8))) _Float16 f16x8;
typedef __attribute__((ext_vector_type(4))) float f32x4;

#define TT 4
#define BB 16
#define CC 384

// ---------- LIF step helpers (mirror reference op order, no fma contraction) ----------
__device__ __forceinline__ float lif_soft(float x, float& v) {
  v = __fadd_rn(v, __fmul_rn(__fsub_rn(x, v), 0.5f));
  float s = (__fsub_rn(v, 1.0f) >= 0.0f) ? 1.0f : 0.0f;
  v = __fsub_rn(v, s);
  return s;
}
__device__ __forceinline__ float lif_hard(float x, float& v, float vth) {
  v = __fadd_rn(v, __fmul_rn(__fsub_rn(x, v), 0.5f));
  float s = (__fsub_rn(v, vth) >= 0.0f) ? 1.0f : 0.0f;
  if (s != 0.0f) v = 0.0f;
  return s;
}

// ---------- BN param folding (double precision) ----------
__global__ __launch_bounds__(768) void k_prep(const float* __restrict__ bn1,
                                              const float* __restrict__ bn2,
                                              const float* __restrict__ qkv,
                                              const float* __restrict__ rbn1,
                                              const float* __restrict__ rbn2,
                                              const float* __restrict__ proj,
                                              float* __restrict__ par) {
  int c = threadIdx.x;
  float* s1 = par;          float* o1 = par + 384;
  float* sA = par + 768;    float* oA = par + 1536;
  float* s2 = par + 2304;   float* o2 = par + 2688;
  float* sB = par + 3072;   float* oB = par + 3456;
  if (c < 384) {
    double a = (double)bn1[c] / sqrt((double)bn1[3*384+c] + 1e-5);
    s1[c] = (float)a;
    o1[c] = (float)((double)bn1[384+c] - (double)bn1[2*384+c]*a);
    double a2 = (double)rbn1[c] / sqrt((double)rbn1[3*384+c] + 1e-5);
    s2[c] = (float)a2;
    o2[c] = (float)((double)rbn1[384+c] - (double)rbn1[2*384+c]*a2);
    double a3 = (double)rbn2[c] / sqrt((double)rbn2[3*384+c] + 1e-5);
    double b3 = (double)rbn2[384+c] - (double)rbn2[2*384+c]*a3;
    double a4 = (double)proj[c] / sqrt((double)proj[3*384+c] + 1e-5);
    double b4 = (double)proj[384+c] - (double)proj[2*384+c]*a4;
    sB[c] = (float)(a3*a4);
    oB[c] = (float)(b3*a4 + b4);
  }
  if (c < 768) {
    double a5 = (double)bn2[c] / sqrt((double)bn2[3*768+c] + 1e-5);
    double b5 = (double)bn2[768+c] - (double)bn2[2*768+c]*a5;
    double a6 = (double)qkv[c] / sqrt((double)qkv[3*768+c] + 1e-5);
    double b6 = (double)qkv[768+c] - (double)qkv[2*768+c]*a6;
    sA[c] = (float)(a5*a6);
    oA[c] = (float)(b5*a6 + b6);
  }
}

// ---------- weight split: w = a + 2^-11 * b ----------
__global__ __launch_bounds__(256) void k_wsplit(const float* __restrict__ w,
                                                f16* __restrict__ wa, f16* __restrict__ wb, int n) {
  int i = blockIdx.x * 256 + threadIdx.x;
  if (i < n) {
    float x = w[i];
    f16 a = (f16)x;
    wa[i] = a;
    wb[i] = (f16)((x - (float)a) * 2048.0f);
  }
}

// ---------- input LIF: NCHW fp32 -> NHWC f16 spikes (LDS transpose) ----------
__global__ __launch_bounds__(256) void k_lif_in(const float* __restrict__ x, f16* __restrict__ xs) {
  __shared__ float tile[64][65];   // [c][p]
  const int p0 = blockIdx.x * 64, c0 = blockIdx.y * 64, b = blockIdx.z;
  const int l = threadIdx.x & 63, q = threadIdx.x >> 6;
  float v[16];
  #pragma unroll
  for (int j = 0; j < 16; ++j) v[j] = 0.0f;
  for (int t = 0; t < TT; ++t) {
    __syncthreads();
    #pragma unroll
    for (int j = 0; j < 16; ++j) {
      int ci = q + j*4;
      tile[ci][l] = x[(((size_t)(t*BB + b)*CC + c0 + ci) << 10) + p0 + l];
    }
    __syncthreads();
    #pragma unroll
    for (int j = 0; j < 16; ++j) {
      int pi = q + j*4;
      float s = lif_hard(tile[l][pi], v[j], 1.0f);
      xs[((size_t)(t*BB + b)*1024 + p0 + pi)*CC + c0 + l] = (f16)s;
    }
  }
}

// ---------- staging: global -> LDS, 64B rows, swizzle col ^= ((row>>1)&3)<<4 ----------
// LDS[row][col] = G[row0+row][k0bytes + (col ^ sw(row))]; involution applied again on read.
__device__ __forceinline__ void stage_arr(const f16* __restrict__ g, int row0, int k0,
                                          f16* dst, int lane, int i0, int i1) {
  #pragma unroll
  for (int i = i0; i < i1; ++i) {
    int loff = i*1024 + lane*16;              // linear byte offset within 8 KB tile
    int row = loff >> 6, col = loff & 63;
    int scol = col ^ (((row >> 1) & 3) << 4); // inverse-swizzled SOURCE column
    const char* src = (const char*)g + (size_t)(row0 + row)*768 + (size_t)(k0*2) + scol;
    __builtin_amdgcn_global_load_lds((const __attribute__((address_space(1))) void*)src,
                                     (__attribute__((address_space(3))) void*)((char*)dst + i*1024),
                                     16, 0, 0);
  }
}

// fragment read with matching swizzle (row in [0,128), fq selects 16B k-slot)
__device__ __forceinline__ f16x8 fragld32(const f16* arr, int row, int fq) {
  int off = row*64 + ((fq*16) ^ (((row >> 1) & 3) << 4));
  return *(const f16x8*)((const char*)arr + off);
}

// ---------- split-f16 MFMA GEMM, 2-phase double-buffered pipeline (BK=32) ----------
// out[m][o] = bn( sum_c X[m][c]*W[o][c] );  X = X1 + 2^-11 X2 (NP==3) or exact X1 (NP==2).
// XCD-chunked block swizzle (m204 bijective, nwg%8==0): the o-blocks sharing an
// X m-row co-reside on one XCD -> X panel is an L2 hit for all but the first.
template<int NP>
__global__ __launch_bounds__(256, 2) void k_gemm(const f16* __restrict__ X1, const f16* __restrict__ X2,
    const f16* __restrict__ Wa, const f16* __restrict__ Wb,
    const float* __restrict__ scale, const float* __restrict__ bias,
    float* __restrict__ out0, float* __restrict__ out1) {
  constexpr int ARR = (NP == 3) ? 4 : 3;            // tiles per buffer
  __shared__ __align__(16) f16 lds[2*ARR*4096];     // 8 KB per tile (128 rows x 64 B)
  const int gx = gridDim.x;
  const int bid = blockIdx.y * gx + blockIdx.x;
  const int chunk = (gx * gridDim.y) >> 3;          // nwg % 8 == 0 for all our grids
  const int nb = (bid & 7) * chunk + (bid >> 3);    // chunked per-XCD, x fastest inside
  const int m0 = (nb / gx) * 128;
  const int o0 = (nb % gx) * 128;
  const int lane = threadIdx.x & 63, wid = threadIdx.x >> 6;
  const int wr = wid >> 1, wc = wid & 1;
  const int fr = lane & 15, fq = lane >> 4;
  f32x4 acc_h[4][4], acc_l[4][4];
  #pragma unroll
  for (int i = 0; i < 4; ++i)
    #pragma unroll
    for (int j = 0; j < 4; ++j) { acc_h[i][j] = (f32x4){0,0,0,0}; acc_l[i][j] = (f32x4){0,0,0,0}; }

  auto stage_all = [&](int buf, int k0) {
    f16* base = lds + buf*(ARR*4096);
    if (NP == 3) {
      if (wid == 0)      stage_arr(X1, m0, k0, base,          lane, 0, 8);
      else if (wid == 1) stage_arr(X2, m0, k0, base + 4096,   lane, 0, 8);
      else if (wid == 2) stage_arr(Wa, o0, k0, base + 2*4096, lane, 0, 8);
      else               stage_arr(Wb, o0, k0, base + 3*4096, lane, 0, 8);
    } else {
      if (wid == 0)      stage_arr(X1, m0, k0, base,          lane, 0, 4);
      else if (wid == 1) stage_arr(X1, m0, k0, base,          lane, 4, 8);
      else if (wid == 2) stage_arr(Wa, o0, k0, base + 4096,   lane, 0, 8);
      else               stage_arr(Wb, o0, k0, base + 2*4096, lane, 0, 8);
    }
  };

  // prologue: stage K-tile 0 into buf 0 (syncthreads drains vmcnt+lgkmcnt)
  stage_all(0, 0);
  __syncthreads();

  for (int it = 0; it < 12; ++it) {                 // K = 384 = 12 x 32
    const int cur = it & 1;
    if (it < 11) stage_all(cur ^ 1, (it + 1)*32);   // issue next tile FIRST (hides HBM latency)
    const f16* bX1 = lds + cur*(ARR*4096);
    const f16* bW1 = (NP == 3) ? bX1 + 2*4096 : bX1 + 4096;
    const f16* bW2 = (NP == 3) ? bX1 + 3*4096 : bX1 + 2*4096;
    f16x8 a1[4], b1[4], b2[4];
    #pragma unroll
    for (int mi = 0; mi < 4; ++mi) a1[mi] = fragld32(bX1, wr*64 + mi*16 + fr, fq);
    #pragma unroll
    for (int oi = 0; oi < 4; ++oi) {
      b1[oi] = fragld32(bW1, wc*64 + oi*16 + fr, fq);
      b2[oi] = fragld32(bW2, wc*64 + oi*16 + fr, fq);
    }
    if (NP == 3) {
      const f16* bX2 = bX1 + 4096;
      f16x8 a2[4];
      #pragma unroll
      for (int mi = 0; mi < 4; ++mi) a2[mi] = fragld32(bX2, wr*64 + mi*16 + fr, fq);
      #pragma unroll
      for (int mi = 0; mi < 4; ++mi)
        #pragma unroll
        for (int oi = 0; oi < 4; ++oi) {
          acc_h[mi][oi] = __builtin_amdgcn_mfma_f32_16x16x32_f16(a1[mi], b1[oi], acc_h[mi][oi], 0, 0, 0);
          acc_l[mi][oi] = __builtin_amdgcn_mfma_f32_16x16x32_f16(a1[mi], b2[oi], acc_l[mi][oi], 0, 0, 0);
          acc_l[mi][oi] = __builtin_amdgcn_mfma_f32_16x16x32_f16(a2[mi], b1[oi], acc_l[mi][oi], 0, 0, 0);
        }
    } else {
      #pragma unroll
      for (int mi = 0; mi < 4; ++mi)
        #pragma unroll
        for (int oi = 0; oi < 4; ++oi) {
          acc_h[mi][oi] = __builtin_amdgcn_mfma_f32_16x16x32_f16(a1[mi], b1[oi], acc_h[mi][oi], 0, 0, 0);
          acc_l[mi][oi] = __builtin_amdgcn_mfma_f32_16x16x32_f16(a1[mi], b2[oi], acc_l[mi][oi], 0, 0, 0);
        }
    }
    __syncthreads();   // drains this wave's stage loads (vmcnt) + releases buf for overwrite
  }

  #pragma unroll
  for (int oi = 0; oi < 4; ++oi) {
    int o = o0 + wc*64 + oi*16 + fr;
    float sc = scale[o], bi = bias[o];
    float* op = out0; int oc = o;
    if (o >= 384) { op = out1; oc = o - 384; }
    #pragma unroll
    for (int mi = 0; mi < 4; ++mi) {
      f32x4 h = acc_h[mi][oi], lo2 = acc_l[mi][oi];
      #pragma unroll
      for (int r = 0; r < 4; ++r) {
        int m = m0 + wr*64 + mi*16 + fq*4 + r;
        float y = fmaf(0.00048828125f, lo2[r], h[r]);   // + 2^-11 * low
        op[(size_t)m*384 + oc] = fmaf(y, sc, bi);
      }
    }
  }
}

// ---------- depthwise 3x3, NHWC, fp32 in -> split-f16 pair out, virtual pad pv[c] ----------
__global__ __launch_bounds__(256) void k_dw(const float* __restrict__ in, const float* __restrict__ wd,
                                            const float* __restrict__ pv,
                                            f16* __restrict__ outA, f16* __restrict__ outB) {
  const int ct = blockIdx.x, h = blockIdx.y, n = blockIdx.z;
  const int c = ct*64 + (threadIdx.x & 63);
  const int wq = threadIdx.x >> 6;
  float w9[9];
  #pragma unroll
  for (int i = 0; i < 9; ++i) w9[i] = wd[c*9 + i];
  const float pvc = pv[c];
  const float* base = in + (size_t)n*1024*CC;
  for (int wi = 0; wi < 8; ++wi) {
    int w = wq*8 + wi;
    float acc = 0.0f;
    #pragma unroll
    for (int dh = -1; dh <= 1; ++dh)
      #pragma unroll
      for (int dw = -1; dw <= 1; ++dw) {
        int hh = h + dh, ww = w + dw;
        float vv = ((unsigned)hh < 32u && (unsigned)ww < 32u) ? base[(size_t)(hh*32 + ww)*CC + c] : pvc;
        acc = fmaf(w9[(dh+1)*3 + dw + 1], vv, acc);
      }
    f16 a = (f16)acc;
    size_t off = ((size_t)n*1024 + h*32 + w)*CC + c;
    outA[off] = a;
    outB[off] = (f16)((acc - (float)a) * 2048.0f);
  }
}

// ---------- qk path stage 1: LIF(soft) + spatial partial sums ----------
__global__ __launch_bounds__(256) void k_qksum(const float* __restrict__ y6qk, float* __restrict__ partial) {
  __shared__ float red[4][4][64];
  const int ps = blockIdx.x, ct = blockIdx.y, b = blockIdx.z;
  const int l = threadIdx.x & 63, pg = threadIdx.x >> 6;
  const int c = ct*64 + l;
  float sums[4] = {0,0,0,0};
  for (int i = 0; i < 32; ++i) {
    int p = ps*128 + pg*32 + i;
    float v = 0.0f;
    #pragma unroll
    for (int t = 0; t < TT; ++t) {
      float xv = y6qk[((size_t)(t*BB + b)*1024 + p)*CC + c];
      sums[t] += lif_soft(xv, v);
    }
  }
  #pragma unroll
  for (int t = 0; t < TT; ++t) red[pg][t][l] = sums[t];
  __syncthreads();
  int t2 = threadIdx.x >> 6;
  float tot = red[0][t2][l] + red[1][t2][l] + red[2][t2][l] + red[3][t2][l];
  partial[(((size_t)ps*4 + t2)*BB + b)*CC + c] = tot;
}

// ---------- qk path stage 2: combine slices + LIF(hard 0.5) -> gate ----------
__global__ __launch_bounds__(256) void k_gate(const float* __restrict__ partial, float* __restrict__ gate) {
  int g = blockIdx.x*256 + threadIdx.x;   // 6144 = 16*384
  int b = g / CC, c = g % CC;
  float sums[4];
  #pragma unroll
  for (int t = 0; t < TT; ++t) {
    float s = 0.0f;
    for (int ps = 0; ps < 8; ++ps) s += partial[(((size_t)ps*4 + t)*BB + b)*CC + c];
    sums[t] = s;
  }
  float v = 0.0f;
  #pragma unroll
  for (int t = 0; t < TT; ++t)
    gate[(size_t)(t*BB + b)*CC + c] = lif_hard(sums[t], v, 0.5f);
}

// ---------- v path: LIF(soft) * gate -> att (exact f16 0/1) ----------
__global__ __launch_bounds__(256) void k_vatt(const float* __restrict__ y6v, const float* __restrict__ gate,
                                              f16* __restrict__ att) {
  const int psl = blockIdx.x, ct = blockIdx.y, b = blockIdx.z;
  const int l = threadIdx.x & 63, pg = threadIdx.x >> 6;
  const int c = ct*64 + l;
  float g4[4];
  #pragma unroll
  for (int t = 0; t < TT; ++t) g4[t] = gate[(size_t)(t*BB + b)*CC + c];
  for (int i = 0; i < 16; ++i) {
    int p = psl*64 + pg*16 + i;
    float v = 0.0f;
    #pragma unroll
    for (int t = 0; t < TT; ++t) {
      size_t off = ((size_t)(t*BB + b)*1024 + p)*CC + c;
      float s = lif_soft(y6v[off], v);
      att[off] = (f16)(s * g4[t]);
    }
  }
}

// ---------- output LIF: NHWC fp32 -> NCHW fp32, soft LIF * scale (LDS transpose) ----------
__global__ __launch_bounds__(256) void k_lif_out(const float* __restrict__ z, const float* __restrict__ scalep,
                                                 float* __restrict__ out) {
  __shared__ float tile[64][65];  // [p][c]
  const int p0 = blockIdx.x * 64, c0 = blockIdx.y * 64, b = blockIdx.z;
  const int l = threadIdx.x & 63, q = threadIdx.x >> 6;
  const float sc = scalep[0];
  float v[16];
  #pragma unroll
  for (int j = 0; j < 16; ++j) v[j] = 0.0f;
  for (int t = 0; t < TT; ++t) {
    __syncthreads();
    #pragma unroll
    for (int j = 0; j < 16; ++j) {
      int pi = q + j*4;
      tile[pi][l] = z[((size_t)(t*BB + b)*1024 + p0 + pi)*CC + c0 + l];
    }
    __syncthreads();
    #pragma unroll
    for (int j = 0; j < 16; ++j) {
      int ci = q + j*4;
      float s = lif_soft(tile[l][ci], v[j]) * sc;
      out[(((size_t)(t*BB + b))*CC + c0 + ci)*1024 + p0 + l] = s;
    }
  }
}

extern "C" void kernel_launch(void* const* d_in, const int* in_sizes, int n_in,
                              void* d_out, int out_size, void* d_ws, size_t ws_size,
                              hipStream_t stream) {
  const float* x      = (const float*)d_in[0];
  const float* r1_w1  = (const float*)d_in[1];
  const float* r1_bn1 = (const float*)d_in[2];
  const float* r1_dw  = (const float*)d_in[3];
  const float* r1_pw  = (const float*)d_in[4];
  const float* r1_bn2 = (const float*)d_in[5];
  const float* qkv_bn = (const float*)d_in[6];
  const float* r2_w1  = (const float*)d_in[7];
  const float* r2_bn1 = (const float*)d_in[8];
  const float* r2_dw  = (const float*)d_in[9];
  const float* r2_pw  = (const float*)d_in[10];
  const float* r2_bn2 = (const float*)d_in[11];
  const float* proj_bn= (const float*)d_in[12];
  const float* scale  = (const float*)d_in[13];

  float* ws = (float*)d_ws;
  const size_t SEG = 12582912;              // 48 MB in floats
  float* W0f = ws;
  float* W1  = ws + SEG;
  float* W2f = ws + 3*SEG;
  float* W3  = ws + 4*SEG;
  f16* xs   = (f16*)W0f;                    // spikes -> p1a -> p2b
  f16* p1a  = (f16*)W0f;
  f16* p2b  = (f16*)W0f;
  f16* p1b  = (f16*)W2f;                    // -> att -> p2a
  f16* att  = (f16*)W2f;
  f16* p2a  = (f16*)W2f;
  float* t1   = W1;                         // gemm1 out -> y6qk -> t2
  float* y6qk = W1;
  float* t2   = W1;
  float* y6v  = W3;                         // -> z
  float* z    = W3;

  f16* wsp = (f16*)(ws + 6*SEG);            // shared region (phases A/B/C)
  f16* w1a = wsp,            *w1b = wsp + 147456;
  f16* pwa = wsp + 294912,   *pwb = wsp + 589824;        // phase A (r1)
  float* partial = (float*)wsp;                          // phase B: 196608 floats
  float* gate    = (float*)wsp + 196608;                 //          +24576
  f16* q1a = wsp,            *q1b = wsp + 147456;        // phase C (r2)
  f16* qpa = wsp + 294912,   *qpb = wsp + 442368;

  float* par = ws + 6*SEG + 442368;         // 3840 floats of BN params
  float* s1 = par,        *o1 = par + 384;
  float* sA = par + 768,  *oA = par + 1536;
  float* s2 = par + 2304, *o2 = par + 2688;
  float* sB = par + 3072, *oB = par + 3456;

  k_prep<<<1, 768, 0, stream>>>(r1_bn1, r1_bn2, qkv_bn, r2_bn1, r2_bn2, proj_bn, par);
  k_wsplit<<<576, 256, 0, stream>>>(r1_w1, w1a, w1b, 147456);
  k_wsplit<<<1152, 256, 0, stream>>>(r1_pw, pwa, pwb, 294912);
  k_lif_in<<<dim3(16, 6, 16), 256, 0, stream>>>(x, xs);
  // repconv1
  k_gemm<2><<<dim3(3, 512), 256, 0, stream>>>(xs, (const f16*)nullptr, w1a, w1b, s1, o1, t1, t1);
  k_dw<<<dim3(6, 32, 64), 256, 0, stream>>>(t1, r1_dw, o1, p1a, p1b);
  k_gemm<3><<<dim3(6, 512), 256, 0, stream>>>(p1a, p1b, pwa, pwb, sA, oA, y6qk, y6v);
  // spike attention gating
  k_qksum<<<dim3(8, 6, 16), 256, 0, stream>>>(y6qk, partial);
  k_gate<<<24, 256, 0, stream>>>(partial, gate);
  k_vatt<<<dim3(16, 6, 16), 256, 0, stream>>>(y6v, gate, att);
  // repconv2 (re-split r2 weights into the shared region after gate consumed)
  k_wsplit<<<576, 256, 0, stream>>>(r2_w1, q1a, q1b, 147456);
  k_wsplit<<<576, 256, 0, stream>>>(r2_pw, qpa, qpb, 147456);
  k_gemm<2><<<dim3(3, 512), 256, 0, stream>>>(att, (const f16*)nullptr, q1a, q1b, s2, o2, t2, t2);
  k_dw<<<dim3(6, 32, 64), 256, 0, stream>>>(t2, r2_dw, o2, p2a, p2b);
  k_gemm<3><<<dim3(3, 512), 256, 0, stream>>>(p2a, p2b, qpa, qpb, sB, oB, z, z);
  // output LIF * scale (NHWC -> NCHW)
  k_lif_out<<<dim3(16, 6, 16), 256, 0, stream>>>(z, scale, (float*)d_out);
}